// Round 1
// baseline (279.851 us; speedup 1.0000x reference)
//
#include <hip/hip_runtime.h>

// Problem constants
#define B_ 2048
#define S_ 512
#define I_ 256
#define F_ 256

// Workspace layout (in floats)
#define OFF_R    0                       // r[512] = Wfc @ W2 ; r_h = r[0:256], r_v = r[256:512]
#define OFF_C0   512                     // const0 = Wfc.b2 + bfc
#define OFF_RS   513                     // R = sum(r_v)
#define OFF_W    1024                    // w[B,F]   (hidden @ W1^T)
#define OFF_SW   (OFF_W + B_*F_)         // Sw[B]    (row sums of w)
#define OFF_U    (OFF_SW + B_)           // u[B,S]
#define OFF_P    (OFF_U + B_*S_)         // p[B,S]
// total floats = OFF_P + B_*S_ = 2,624,512  (~10.5 MB)

// ---------------------------------------------------------------------------
// K0: r[j] = sum_i Wfc[i]*W2[i,j];  const0 = Wfc.b2 + bfc;  R = sum_{j>=256} r[j]
// one block, 512 threads
__global__ __launch_bounds__(512) void k0_fold(
    const float* __restrict__ W2, const float* __restrict__ b2,
    const float* __restrict__ Wfc, const float* __restrict__ bfc,
    float* __restrict__ ws) {
  const int j = threadIdx.x;
  float acc = 0.f;
#pragma unroll 8
  for (int i = 0; i < I_; ++i) acc += Wfc[i] * W2[i * (I_ + F_) + j];
  ws[OFF_R + j] = acc;

  __shared__ float red[512];
  // const0
  red[j] = (j < I_) ? Wfc[j] * b2[j] : 0.f;
  __syncthreads();
  for (int s = 256; s > 0; s >>= 1) { if (j < s) red[j] += red[j + s]; __syncthreads(); }
  if (j == 0) ws[OFF_C0] = red[0] + bfc[0];
  __syncthreads();
  // R = sum of r_v
  red[j] = (j >= I_) ? acc : 0.f;
  __syncthreads();
  for (int s = 256; s > 0; s >>= 1) { if (j < s) red[j] += red[j + s]; __syncthreads(); }
  if (j == 0) ws[OFF_RS] = red[0];
}

// ---------------------------------------------------------------------------
// Kw: w[b,f] = hidden[b,:].W1[f,:] ;  Sw[b] = sum_f w[b,f]
// grid B/4, block 256 (4 batches per block to amortize W1 reads)
__global__ __launch_bounds__(256) void kw_lin1(
    const float* __restrict__ hidden, const float* __restrict__ W1,
    float* __restrict__ ws) {
  const int b0 = blockIdx.x * 4;
  const int tid = threadIdx.x;
  __shared__ float h[4][I_];
#pragma unroll
  for (int k = 0; k < 4; ++k) h[k][tid] = hidden[(size_t)(b0 + k) * I_ + tid];
  __syncthreads();

  const int f = tid;
  const float4* wrow = (const float4*)(W1 + (size_t)f * I_);
  float acc[4] = {0.f, 0.f, 0.f, 0.f};
#pragma unroll 4
  for (int iq = 0; iq < I_ / 4; ++iq) {
    const float4 v = wrow[iq];
    const int i = 4 * iq;
#pragma unroll
    for (int k = 0; k < 4; ++k)
      acc[k] += v.x * h[k][i] + v.y * h[k][i + 1] + v.z * h[k][i + 2] + v.w * h[k][i + 3];
  }
#pragma unroll
  for (int k = 0; k < 4; ++k) ws[OFF_W + (size_t)(b0 + k) * F_ + f] = acc[k];

  __shared__ float red[256];
#pragma unroll
  for (int k = 0; k < 4; ++k) {
    red[tid] = acc[k];
    __syncthreads();
    for (int s = 128; s > 0; s >>= 1) { if (tid < s) red[tid] += red[tid + s]; __syncthreads(); }
    if (tid == 0) ws[OFF_SW + b0 + k] = red[0];
    __syncthreads();
  }
}

// ---------------------------------------------------------------------------
// K1: the single pass over inp (1 GB).
//   u[b,t] = inp[b,t,:] . w[b,:]
//   p[b,t] = inp[b,t,:] . r_v[:]
// grid (S/32, B), block 256 = 4 waves; each wave handles 8 rows (one row = 256 f32 = 1 KB,
// loaded as one float4 per lane), two dots reduced with 64-lane shfl_xor.
__global__ __launch_bounds__(256) void k1_scan(
    const float* __restrict__ inp, float* __restrict__ ws) {
  const int ROWS = 32;
  const int b = blockIdx.y;
  const int t0 = blockIdx.x * ROWS;
  const int lane = threadIdx.x & 63;
  const int wid = threadIdx.x >> 6;

  const float4 w4  = ((const float4*)(ws + OFF_W + (size_t)b * F_))[lane];
  const float4 rv4 = ((const float4*)(ws + OFF_R + 256))[lane];
  const float* base = inp + ((size_t)b * S_ + t0) * I_;
  float* uo = ws + OFF_U + (size_t)b * S_ + t0;
  float* po = ws + OFF_P + (size_t)b * S_ + t0;

#pragma unroll
  for (int rr = 0; rr < ROWS / 4; ++rr) {
    const int row = wid + 4 * rr;
    const float4 in4 = ((const float4*)(base + (size_t)row * I_))[lane];
    float du = in4.x * w4.x + in4.y * w4.y + in4.z * w4.z + in4.w * w4.w;
    float dp = in4.x * rv4.x + in4.y * rv4.y + in4.z * rv4.z + in4.w * rv4.w;
#pragma unroll
    for (int m = 32; m >= 1; m >>= 1) {
      du += __shfl_xor(du, m, 64);
      dp += __shfl_xor(dp, m, 64);
    }
    if (lane == 0) { uo[row] = du; po[row] = dp; }
  }
}

// ---------------------------------------------------------------------------
// K2: per-batch epilogue.
//   s[x] = Wc[x,:].u[b,:] + bc[x]*Sw[b];  q[x] = Wc[x,:].p[b,:]
//   a = sigmoid(s); out[b] = r_h.hidden[b] + sum_x a[x]*(q[x] + bc[x]*R) + const0
// grid B/4, block 256 (thread = x); 4 batches per block amortize the Wc sweep.
__global__ __launch_bounds__(256) void k2_epilogue(
    const float* __restrict__ Wc, const float* __restrict__ bc,
    const float* __restrict__ hidden, const float* __restrict__ ws,
    float* __restrict__ out) {
  const int b0 = blockIdx.x * 4;
  const int tid = threadIdx.x;
  __shared__ float u[4][S_];
  __shared__ float p[4][S_];
  const float* wsu = ws + OFF_U;
  const float* wsp = ws + OFF_P;
#pragma unroll
  for (int k = 0; k < 4; ++k) {
    u[k][tid]       = wsu[(size_t)(b0 + k) * S_ + tid];
    u[k][tid + 256] = wsu[(size_t)(b0 + k) * S_ + tid + 256];
    p[k][tid]       = wsp[(size_t)(b0 + k) * S_ + tid];
    p[k][tid + 256] = wsp[(size_t)(b0 + k) * S_ + tid + 256];
  }
  __syncthreads();

  const int x = tid;
  const float4* wrow = (const float4*)(Wc + (size_t)x * S_);
  float ss[4] = {0.f, 0.f, 0.f, 0.f};
  float qs[4] = {0.f, 0.f, 0.f, 0.f};
#pragma unroll 4
  for (int tq = 0; tq < S_ / 4; ++tq) {
    const float4 v = wrow[tq];
    const int t = 4 * tq;
#pragma unroll
    for (int k = 0; k < 4; ++k) {
      ss[k] += v.x * u[k][t] + v.y * u[k][t + 1] + v.z * u[k][t + 2] + v.w * u[k][t + 3];
      qs[k] += v.x * p[k][t] + v.y * p[k][t + 1] + v.z * p[k][t + 2] + v.w * p[k][t + 3];
    }
  }

  const float bcx = bc[x];
  const float R   = ws[OFF_RS];
  const float rh  = ws[OFF_R + x];
  const float c0  = ws[OFF_C0];

  __shared__ float red[256];
#pragma unroll
  for (int k = 0; k < 4; ++k) {
    const float Sw = ws[OFF_SW + b0 + k];
    const float s  = ss[k] + bcx * Sw;
    const float a  = 1.f / (1.f + expf(-s));
    float partial  = a * (qs[k] + bcx * R) + rh * hidden[(size_t)(b0 + k) * I_ + x];
    red[tid] = partial;
    __syncthreads();
    for (int st = 128; st > 0; st >>= 1) { if (tid < st) red[tid] += red[tid + st]; __syncthreads(); }
    if (tid == 0) out[b0 + k] = red[0] + c0;
    __syncthreads();
  }
}

// ---------------------------------------------------------------------------
extern "C" void kernel_launch(void* const* d_in, const int* in_sizes, int n_in,
                              void* d_out, int out_size, void* d_ws, size_t ws_size,
                              hipStream_t stream) {
  (void)in_sizes; (void)n_in; (void)out_size; (void)ws_size;
  const float* hidden = (const float*)d_in[0];
  const float* inp    = (const float*)d_in[1];
  const float* W1     = (const float*)d_in[2];
  const float* Wc     = (const float*)d_in[3];
  const float* bc     = (const float*)d_in[4];
  const float* W2     = (const float*)d_in[5];
  const float* b2     = (const float*)d_in[6];
  const float* Wfc    = (const float*)d_in[7];
  const float* bfc    = (const float*)d_in[8];
  float* out = (float*)d_out;
  float* ws  = (float*)d_ws;

  hipLaunchKernelGGL(k0_fold, dim3(1), dim3(512), 0, stream, W2, b2, Wfc, bfc, ws);
  hipLaunchKernelGGL(kw_lin1, dim3(B_ / 4), dim3(256), 0, stream, hidden, W1, ws);
  hipLaunchKernelGGL(k1_scan, dim3(S_ / 32, B_), dim3(256), 0, stream, inp, ws);
  hipLaunchKernelGGL(k2_epilogue, dim3(B_ / 4), dim3(256), 0, stream, Wc, bc, hidden, ws, out);
}